// Round 4
// baseline (241.390 us; speedup 1.0000x reference)
//
#include <hip/hip_runtime.h>
#include <math.h>

#define BB 2
#define SS 2048
#define DD 1024
#define HH 16

typedef unsigned short u16;
using bf16x8 = __attribute__((ext_vector_type(8))) short;   // 8 bf16 in 4 VGPRs
using f32x4  = __attribute__((ext_vector_type(4))) float;   // MFMA accumulator

#define LOG2E 1.44269504f

// ---------------- workspace layout ----------------
// f32: cosT[32][2048] @ 0, sinT[32][2048] @ 65536, mbias[B*S] @ 131072 (4096)
// u16 region from float offset 135168:
//   xb   [4096][1024]   (reused as vtbuf after qkv_gemm)
//   wtq/wtk/wtv/wto [1024][1024]  transposed weights [n][k]
//   qbuf [B,H,S,64]  RoPE'd, x(0.125*log2e)
//   kbuf [B,H,S,64]  RoPE'd
//   vbuf [B,H,S,64]  row-major V
//   preb [4096][1024]
// total ~50.6 MiB

__device__ __forceinline__ u16 f2bf(float f) {   // round-to-nearest-even
    unsigned u = __float_as_uint(f);
    unsigned r = u + 0x7fffu + ((u >> 16) & 1u);
    return (u16)(r >> 16);
}

// async global->LDS, 16B per lane; LDS dest pattern = wave-uniform base + lane*16
__device__ __forceinline__ void gload_lds16(const void* g, const void* l) {
    __builtin_amdgcn_global_load_lds(
        (const __attribute__((address_space(1))) unsigned int*)(unsigned long long)g,
        (__attribute__((address_space(3))) unsigned int*)(unsigned int)(unsigned long long)l,
        16, 0, 0);
}

// ---------------- 1) RoPE table (TRANSPOSED: [32 angle][2048 pos]) ----------------
__global__ void rope_table(float* __restrict__ cost, float* __restrict__ sint) {
    int idx = blockIdx.x * 256 + threadIdx.x;   // 65536 exact
    int j   = idx >> 11;      // angle index 0..31
    int pos = idx & 2047;
    double inv = pow(10000.0, -(double)j / 32.0);
    double ang = (double)pos * inv;
    cost[idx] = (float)cos(ang);
    sint[idx] = (float)sin(ang);
}

// ---------------- 1b) mask -> log2-domain bias table ----------------
__global__ void mkbias(const int* __restrict__ mask, float* __restrict__ mb) {
    int i = blockIdx.x * 256 + threadIdx.x;   // 4096 exact
    mb[i] = -1.44269504e9f * (float)mask[i];  // -1e9 * log2e * mask
}

// ---------------- 2) x -> bf16 ----------------
__global__ void cvt_x(const float* __restrict__ x, u16* __restrict__ xb) {
    int i = (blockIdx.x * 256 + threadIdx.x) * 4;
    float4 v = *(const float4*)(x + i);
    ushort4 o;
    o.x = f2bf(v.x); o.y = f2bf(v.y); o.z = f2bf(v.z); o.w = f2bf(v.w);
    *(ushort4*)(xb + i) = o;
}

// ---------------- 3) W [K][N] f32 -> Wt [N][K] bf16 ----------------
__global__ void transpose_w(const float* __restrict__ w0, const float* __restrict__ w1,
                            const float* __restrict__ w2, const float* __restrict__ w3,
                            u16* __restrict__ o0, u16* __restrict__ o1,
                            u16* __restrict__ o2, u16* __restrict__ o3) {
    const float* in = (blockIdx.z == 0) ? w0 : (blockIdx.z == 1) ? w1 : (blockIdx.z == 2) ? w2 : w3;
    u16* out        = (blockIdx.z == 0) ? o0 : (blockIdx.z == 1) ? o1 : (blockIdx.z == 2) ? o2 : o3;
    __shared__ float t[32][33];
    int n = blockIdx.x * 32 + threadIdx.x;
    for (int i = threadIdx.y; i < 32; i += 8)
        t[i][threadIdx.x] = in[(size_t)(blockIdx.y * 32 + i) * 1024 + n];
    __syncthreads();
    int k = blockIdx.y * 32 + threadIdx.x;
    for (int i = threadIdx.y; i < 32; i += 8)
        out[(size_t)(blockIdx.x * 32 + i) * 1024 + k] = f2bf(t[threadIdx.x][i]);
}

// ---------------- 4) MFMA GEMM: fused QKV projection + RoPE ----------------
// Q: (acc+bias)->RoPE->x(0.125*log2e); K: RoPE; V: row-major coalesced store.
__global__ __launch_bounds__(256)
void qkv_gemm(const u16* __restrict__ xb,
              const u16* __restrict__ wtq, const u16* __restrict__ wtk, const u16* __restrict__ wtv,
              const float* __restrict__ bq, const float* __restrict__ bk, const float* __restrict__ bv,
              const float* __restrict__ cost, const float* __restrict__ sint,
              u16* __restrict__ qo, u16* __restrict__ ko, u16* __restrict__ vo)
{
    __shared__ u16 Al[128 * 32];
    __shared__ u16 Bl[128 * 32];

    int bx = blockIdx.x;                 // 24: (which 0..2) x (8 n-tiles)
    int which = bx >> 3;
    int n0 = (bx & 7) << 7;
    int m0 = blockIdx.y << 7;
    const u16*  wt    = (which == 0) ? wtq : (which == 1) ? wtk : wtv;
    const float* bias = (which == 0) ? bq  : (which == 1) ? bk  : bv;

    int t = threadIdx.x;
    int wid = t >> 6, lane = t & 63;
    int wr = wid >> 1, wc = wid & 1;
    int fr = lane & 15, fq = lane >> 4;

    f32x4 acc[4][4];
    #pragma unroll
    for (int m = 0; m < 4; ++m)
        #pragma unroll
        for (int n = 0; n < 4; ++n)
            #pragma unroll
            for (int r = 0; r < 4; ++r) acc[m][n][r] = 0.f;

    int srow = (lane >> 2);
    int skof = (lane & 3) << 3;

    for (int k0 = 0; k0 < 1024; k0 += 32) {
        __syncthreads();
        #pragma unroll
        for (int c = 0; c < 2; ++c) {
            int chunk = wid * 2 + c;
            int row = (chunk << 4) + srow;
            gload_lds16(xb + (size_t)(m0 + row) * 1024 + k0 + skof, &Al[chunk << 9]);
            gload_lds16(wt + (size_t)(n0 + row) * 1024 + k0 + skof, &Bl[chunk << 9]);
        }
        __syncthreads();

        bf16x8 af[4], bf[4];
        #pragma unroll
        for (int m = 0; m < 4; ++m)
            af[m] = *(const bf16x8*)&Al[((wr << 6) + (m << 4) + fr) * 32 + (fq << 3)];
        #pragma unroll
        for (int n = 0; n < 4; ++n)
            bf[n] = *(const bf16x8*)&Bl[((wc << 6) + (n << 4) + fr) * 32 + (fq << 3)];
        #pragma unroll
        for (int m = 0; m < 4; ++m)
            #pragma unroll
            for (int n = 0; n < 4; ++n)
                acc[m][n] = __builtin_amdgcn_mfma_f32_16x16x32_bf16(af[m], bf[n], acc[m][n], 0, 0, 0);
    }

    // C row = m0+wr*64+mm*16+fq*4+j ; C col = n0+wc*64+n*16+fr
    if (which < 2) {
        u16* outp = (which == 0) ? qo : ko;
        const float qs = (which == 0) ? 0.125f * LOG2E : 1.0f;   // fold 1/sqrt(64)*log2e into Q
        #pragma unroll
        for (int n = 0; n < 2; ++n) {                    // d = 16n+fr in [0,32); partner acc n+2
            int col = n0 + (wc << 6) + (n << 4) + fr;
            int h = col >> 6;
            int d = col & 63;
            float b1 = bias[col], b2 = bias[col + 32];
            int a1 = d >> 1;
            #pragma unroll
            for (int mm = 0; mm < 4; ++mm) {
                int mi0 = m0 + (wr << 6) + (mm << 4) + (fq << 2);
                int bi = mi0 >> 11, s0 = mi0 & 2047;     // 4-aligned, no 2048-wrap within j
                float4 c1 = *(const float4*)(cost + (a1 << 11) + s0);
                float4 s1 = *(const float4*)(sint + (a1 << 11) + s0);
                float4 c2 = *(const float4*)(cost + ((a1 + 16) << 11) + s0);
                float4 s2 = *(const float4*)(sint + ((a1 + 16) << 11) + s0);
                const float* c1p = (const float*)&c1;
                const float* s1p = (const float*)&s1;
                const float* c2p = (const float*)&c2;
                const float* s2p = (const float*)&s2;
                #pragma unroll
                for (int j = 0; j < 4; ++j) {
                    float x1 = acc[mm][n][j]     + b1;
                    float x2 = acc[mm][n + 2][j] + b2;
                    size_t base = ((size_t)(bi * HH + h) * SS + s0 + j) << 6;
                    outp[base + d]      = f2bf((x1 * c1p[j] - x2 * s1p[j]) * qs);
                    outp[base + d + 32] = f2bf((x2 * c2p[j] + x1 * s2p[j]) * qs);
                }
            }
        }
    } else {
        #pragma unroll
        for (int n = 0; n < 4; ++n) {
            int col = n0 + (wc << 6) + (n << 4) + fr;
            int h = col >> 6, d = col & 63;
            float bb = bias[col];
            #pragma unroll
            for (int mm = 0; mm < 4; ++mm) {
                #pragma unroll
                for (int j = 0; j < 4; ++j) {
                    int mi = m0 + (wr << 6) + (mm << 4) + (fq << 2) + j;
                    int bi = mi >> 11, s = mi & 2047;
                    vo[(((size_t)(bi * HH + h) * SS + s) << 6) + d] = f2bf(acc[mm][n][j] + bb);
                }
            }
        }
    }
}

// ---------------- 4b) V [bh][s][64] -> V^T [bh][64][s] ----------------
__global__ __launch_bounds__(256)
void transpose_v(const u16* __restrict__ vin, u16* __restrict__ vout) {
    __shared__ u16 Ld[64][72];    // 144B rows, 16B-aligned starts
    int stile = blockIdx.x;       // 32
    int bh    = blockIdx.y;       // 32
    int t = threadIdx.x;
    int r = t >> 2, seg = (t & 3) << 4;
    const u16* src = vin + (((size_t)bh * SS + (stile << 6) + r) << 6) + seg;
    *(uint4*)&Ld[r][seg]     = *(const uint4*)src;
    *(uint4*)&Ld[r][seg + 8] = *(const uint4*)(src + 8);
    __syncthreads();
    u16 tmp[16];
    #pragma unroll
    for (int i = 0; i < 16; ++i) tmp[i] = Ld[seg + i][r];
    u16* dst = vout + ((size_t)(bh << 6) + r) * SS + (stile << 6) + seg;
    *(uint4*)dst       = *(const uint4*)&tmp[0];
    *(uint4*)(dst + 8) = *(const uint4*)&tmp[8];
}

// ---------------- 5) MFMA flash attention (exp2-domain softmax) ----------------
// 1D grid 1024, XCD-bijective: all 32 q-blocks of a bh share an XCD's L2.
__global__ __launch_bounds__(256, 4)
void attn(const u16* __restrict__ qb, const u16* __restrict__ kb, const u16* __restrict__ vt,
          const float* __restrict__ mbias, u16* __restrict__ preb)
{
    __shared__ u16 Kl[2][4096];   // [64 key][64 d] bf16, swizzled rows (128B)
    __shared__ u16 Vl[2][4096];   // [64 d][64 key] bf16, swizzled
    __shared__ u16 Pl[4][1024];   // per-wave P [16 q][64 key] bf16, swizzled

    const int bid = blockIdx.x;
    const int xcd = bid & 7;
    const int idx = bid >> 3;
    const int bh  = (xcd << 2) | (idx >> 5);   // 4 bh per XCD -> K/V (2MB) fits 4MB L2
    const int qb0 = (idx & 31) << 6;
    const int b   = bh >> 4;
    const int t   = threadIdx.x;
    const int w   = t >> 6;
    const int lane = t & 63;
    const int fr  = lane & 15;
    const int fq  = lane >> 4;
    const int swz = (fr & 7) << 4;

    const char* kbase = (const char*)(kb + ((size_t)bh << 17));
    const char* vbase = (const char*)(vt + ((size_t)bh << 17));
    const float* mbp  = mbias + (b << 11);

    const int sbo = ((t & 7) << 4) ^ (((t >> 3) & 7) << 4);   // inverse-swizzled src byte

    const int qrow = qb0 + (w << 4) + fr;
    const u16* qp = qb + (((size_t)bh << 11) + qrow) * 64 + (fq << 3);
    bf16x8 qf0 = *(const bf16x8*)qp;
    bf16x8 qf1 = *(const bf16x8*)(qp + 32);

    f32x4 o[4];
    #pragma unroll
    for (int n = 0; n < 4; ++n)
        #pragma unroll
        for (int r = 0; r < 4; ++r) o[n][r] = 0.f;
    float mrun = -INFINITY, lrun = 0.f;

    auto STAGE = [&](int buf, int kt) {
        #pragma unroll
        for (int c = 0; c < 2; ++c) {
            int row = (c << 5) + (t >> 3);
            gload_lds16(kbase + ((size_t)(kt << 6) + row) * 128 + sbo,
                        (const char*)&Kl[buf][0] + (c << 12) + t * 16);
            gload_lds16(vbase + (size_t)row * 4096 + (kt << 7) + sbo,
                        (const char*)&Vl[buf][0] + (c << 12) + t * 16);
        }
    };

    STAGE(0, 0);
    __syncthreads();

    for (int kt = 0; kt < 32; ++kt) {
        const int cur = kt & 1;

        if (kt < 31) STAGE(cur ^ 1, kt + 1);

        // QK^T (swapped): sv[g] = S^T for keys 16g..16g+15, log2-domain (Q pre-scaled)
        f32x4 sv[4];
        #pragma unroll
        for (int g = 0; g < 4; ++g)
            #pragma unroll
            for (int r = 0; r < 4; ++r) sv[g][r] = 0.f;

        const char* Kb = (const char*)&Kl[cur][0];
        __builtin_amdgcn_s_setprio(1);
        #pragma unroll
        for (int g = 0; g < 4; ++g) {
            int row = (g << 4) + fr;
            bf16x8 kf0 = *(const bf16x8*)(Kb + row * 128 + ((fq << 4) ^ swz));
            bf16x8 kf1 = *(const bf16x8*)(Kb + row * 128 + (((fq << 4) + 64) ^ swz));
            sv[g] = __builtin_amdgcn_mfma_f32_16x16x32_bf16(kf0, qf0, sv[g], 0, 0, 0);
            sv[g] = __builtin_amdgcn_mfma_f32_16x16x32_bf16(kf1, qf1, sv[g], 0, 0, 0);
        }
        __builtin_amdgcn_s_setprio(0);

        // bias + row max (keys 16g+4fq+j live in-lane; cross-fq via shfl)
        float tm = -INFINITY;
        #pragma unroll
        for (int g = 0; g < 4; ++g) {
            const float4 m4 = *(const float4*)(mbp + (kt << 6) + (g << 4) + (fq << 2));
            sv[g][0] += m4.x; sv[g][1] += m4.y; sv[g][2] += m4.z; sv[g][3] += m4.w;
            tm = fmaxf(tm, fmaxf(fmaxf(sv[g][0], sv[g][1]), fmaxf(sv[g][2], sv[g][3])));
        }
        tm = fmaxf(tm, __shfl_xor(tm, 16));
        tm = fmaxf(tm, __shfl_xor(tm, 32));

        // defer-max (T13): only rescale when the running max grew materially
        if (!__all(tm <= mrun + 11.0f)) {
            float newm = fmaxf(mrun, tm);
            float scale = __builtin_amdgcn_exp2f(mrun - newm);   // first tile: 0
            lrun *= scale;
            #pragma unroll
            for (int j = 0; j < 4; ++j) {
                float sj = __shfl(scale, (lane & 48) + (fq << 2) + j);
                #pragma unroll
                for (int n = 0; n < 4; ++n) o[n][j] *= sj;
            }
            mrun = newm;
        }

        // P = exp2(sv - mrun)  (bounded by 2^11), pack via v_cvt_pk_bf16_f32
        float ps = 0.f;
        #pragma unroll
        for (int g = 0; g < 4; ++g) {
            float p0 = __builtin_amdgcn_exp2f(sv[g][0] - mrun);
            float p1 = __builtin_amdgcn_exp2f(sv[g][1] - mrun);
            float p2 = __builtin_amdgcn_exp2f(sv[g][2] - mrun);
            float p3 = __builtin_amdgcn_exp2f(sv[g][3] - mrun);
            ps += (p0 + p1) + (p2 + p3);
            unsigned r0, r1;
            asm("v_cvt_pk_bf16_f32 %0, %1, %2" : "=v"(r0) : "v"(p0), "v"(p1));
            asm("v_cvt_pk_bf16_f32 %0, %1, %2" : "=v"(r1) : "v"(p2), "v"(p3));
            uint2 pw; pw.x = r0; pw.y = r1;
            *(uint2*)((char*)&Pl[w][0] + fr * 128 + (((g << 5) + (fq << 3)) ^ swz)) = pw;
        }
        ps += __shfl_xor(ps, 16);
        ps += __shfl_xor(ps, 32);
        lrun += ps;

        // PV: O[q][d] += P[q][k] * V[k][d]
        __builtin_amdgcn_s_setprio(1);
        #pragma unroll
        for (int kk = 0; kk < 2; ++kk) {
            bf16x8 pa = *(const bf16x8*)((const char*)&Pl[w][0] + fr * 128 + (((fq << 4) + (kk << 6)) ^ swz));
            #pragma unroll
            for (int n = 0; n < 4; ++n) {
                int row = (n << 4) + fr;
                bf16x8 vf = *(const bf16x8*)((const char*)&Vl[cur][0] + row * 128 + (((fq << 4) + (kk << 6)) ^ swz));
                o[n] = __builtin_amdgcn_mfma_f32_16x16x32_bf16(pa, vf, o[n], 0, 0, 0);
            }
        }
        __builtin_amdgcn_s_setprio(0);
        __syncthreads();
    }

    // epilogue: lane holds O[q=4fq+j][d=16n+fr]
    #pragma unroll
    for (int j = 0; j < 4; ++j) {
        float lj = __shfl(lrun, (lane & 48) + (fq << 2) + j);
        float inv = 1.0f / lj;
        int qr = qb0 + (w << 4) + (fq << 2) + j;
        u16* op = preb + ((size_t)((b << 11) + qr) << 10) + ((bh & 15) << 6) + fr;
        #pragma unroll
        for (int n = 0; n < 4; ++n)
            op[n << 4] = f2bf(o[n][j] * inv);
    }
}

// ---------------- 6) MFMA GEMM: output projection ----------------
__global__ __launch_bounds__(256)
void out_gemm(const u16* __restrict__ pre, const u16* __restrict__ wto,
              const float* __restrict__ bo, float* __restrict__ outp)
{
    __shared__ u16 Al[128 * 32];
    __shared__ u16 Bl[128 * 32];

    int n0 = blockIdx.x << 7;
    int m0 = blockIdx.y << 7;

    int t = threadIdx.x;
    int wid = t >> 6, lane = t & 63;
    int wr = wid >> 1, wc = wid & 1;
    int fr = lane & 15, fq = lane >> 4;

    f32x4 acc[4][4];
    #pragma unroll
    for (int m = 0; m < 4; ++m)
        #pragma unroll
        for (int n = 0; n < 4; ++n)
            #pragma unroll
            for (int r = 0; r < 4; ++r) acc[m][n][r] = 0.f;

    int srow = (lane >> 2);
    int skof = (lane & 3) << 3;

    for (int k0 = 0; k0 < 1024; k0 += 32) {
        __syncthreads();
        #pragma unroll
        for (int c = 0; c < 2; ++c) {
            int chunk = wid * 2 + c;
            int row = (chunk << 4) + srow;
            gload_lds16(pre + (size_t)(m0 + row) * 1024 + k0 + skof, &Al[chunk << 9]);
            gload_lds16(wto + (size_t)(n0 + row) * 1024 + k0 + skof, &Bl[chunk << 9]);
        }
        __syncthreads();

        bf16x8 af[4], bf[4];
        #pragma unroll
        for (int m = 0; m < 4; ++m)
            af[m] = *(const bf16x8*)&Al[((wr << 6) + (m << 4) + fr) * 32 + (fq << 3)];
        #pragma unroll
        for (int n = 0; n < 4; ++n)
            bf[n] = *(const bf16x8*)&Bl[((wc << 6) + (n << 4) + fr) * 32 + (fq << 3)];
        #pragma unroll
        for (int m = 0; m < 4; ++m)
            #pragma unroll
            for (int n = 0; n < 4; ++n)
                acc[m][n] = __builtin_amdgcn_mfma_f32_16x16x32_bf16(af[m], bf[n], acc[m][n], 0, 0, 0);
    }

    #pragma unroll
    for (int n = 0; n < 4; ++n) {
        int col = n0 + (wc << 6) + (n << 4) + fr;
        float bb = bo[col];
        #pragma unroll
        for (int m = 0; m < 4; ++m) {
            #pragma unroll
            for (int j = 0; j < 4; ++j) {
                int mi = m0 + (wr << 6) + (m << 4) + (fq << 2) + j;
                outp[(size_t)mi * 1024 + col] = acc[m][n][j] + bb;
            }
        }
    }
}

// ---------------- launch ----------------
extern "C" void kernel_launch(void* const* d_in, const int* in_sizes, int n_in,
                              void* d_out, int out_size, void* d_ws, size_t ws_size,
                              hipStream_t stream) {
    const float* x    = (const float*)d_in[0];
    const int*   mask = (const int*)  d_in[1];
    const float* wq   = (const float*)d_in[2];
    const float* bq   = (const float*)d_in[3];
    const float* wk   = (const float*)d_in[4];
    const float* bk   = (const float*)d_in[5];
    const float* wv   = (const float*)d_in[6];
    const float* bv   = (const float*)d_in[7];
    const float* wo   = (const float*)d_in[8];
    const float* bo   = (const float*)d_in[9];
    float* out = (float*)d_out;
    float* ws  = (float*)d_ws;

    float* cosT  = ws;                     // [32][2048]
    float* sinT  = ws + 65536;
    float* mbias = ws + 131072;            // [B*S]
    u16* xb    = (u16*)(ws + 135168);
    u16* wtq   = xb    + 4194304;
    u16* wtk   = wtq   + 1048576;
    u16* wtv   = wtk   + 1048576;
    u16* wto   = wtv   + 1048576;
    u16* qbuf  = wto   + 1048576;
    u16* kbuf  = qbuf  + 4194304;
    u16* vbuf  = kbuf  + 4194304;
    u16* preb  = vbuf  + 4194304;
    u16* vtbuf = xb;                       // xb dead after qkv_gemm

    hipLaunchKernelGGL(rope_table, dim3(256), dim3(256), 0, stream, cosT, sinT);
    hipLaunchKernelGGL(mkbias, dim3(16), dim3(256), 0, stream, mask, mbias);
    hipLaunchKernelGGL(cvt_x, dim3(4096), dim3(256), 0, stream, x, xb);
    hipLaunchKernelGGL(transpose_w, dim3(32, 32, 4), dim3(32, 8), 0, stream,
                       wq, wk, wv, wo, wtq, wtk, wtv, wto);
    hipLaunchKernelGGL(qkv_gemm, dim3(24, 32), dim3(256), 0, stream,
                       xb, wtq, wtk, wtv, bq, bk, bv, cosT, sinT, qbuf, kbuf, vbuf);
    hipLaunchKernelGGL(transpose_v, dim3(32, 32), dim3(256), 0, stream, vbuf, vtbuf);
    hipLaunchKernelGGL(attn, dim3(1024), dim3(256), 0, stream,
                       qbuf, kbuf, vtbuf, mbias, preb);
    hipLaunchKernelGGL(out_gemm, dim3(8, 32), dim3(256), 0, stream, preb, wto, bo, out);
}